// Round 15
// baseline (479.387 us; speedup 1.0000x reference)
//
#include <hip/hip_runtime.h>
#include <hip/hip_bf16.h>
#include <math.h>

#define NU 50000
#define NFOOD 30000
#define NING 20000
#define NCAT 5000
#define NHAB 10000
#define NNODES 115000
#define NCHUNK 14375   // NNODES/8 (XCD dst partition)
#define NREL 8
#define NSEG (NNODES * NREL)   // 920000
#define NEDGE 1500000
#define SCAN_B 256

typedef __attribute__((ext_vector_type(8))) short short8;
typedef __attribute__((ext_vector_type(4))) float f32x4;

static inline size_t alignup(size_t x) { return (x + 255) & ~(size_t)255; }

__device__ inline float bf16_bits_to_f32(unsigned short u) {
  return __uint_as_float(((unsigned)u) << 16);
}
__device__ inline unsigned short f32_to_bf16_bits(float f) {
  unsigned u = __float_as_uint(f);
  unsigned r = u + 0x7fffu + ((u >> 16) & 1u);
  return (unsigned short)(r >> 16);
}
__device__ inline unsigned pack_bf16x2(float lo, float hi) {
  return (unsigned)f32_to_bf16_bits(lo) | ((unsigned)f32_to_bf16_bits(hi) << 16);
}

// ================= MFMA bf16 GEMM (generic; used for layer-2) ======================
template <bool A_F32, bool OUT_BF16, bool RELU_OUT>
__global__ __launch_bounds__(256) void mfma_gemm(
    const void* __restrict__ Ain, const unsigned short* __restrict__ Bt, int ldB,
    const float* __restrict__ bias, void* __restrict__ Cv, int ldC, int Nstore,
    int M, int N, int K) {
  __shared__ char As[128 * 128];
  __shared__ char Bs[128 * 128];
  const int tid = threadIdx.x;
  const int lane = tid & 63;
  const int wv = tid >> 6;
  const int bm = blockIdx.y * 128;
  const int bn = blockIdx.x * 128;
  f32x4 acc[2][8] = {};

  for (int k0 = 0; k0 < K; k0 += 64) {
    if (A_F32) {
      const float* A = (const float*)Ain;
#pragma unroll
      for (int it = 0; it < 4; ++it) {
        int u = it * 256 + tid;
        int m = u >> 3, c = u & 7;
        int mg = bm + m; if (mg >= M) mg = M - 1;
        const float4* src = (const float4*)(A + (size_t)mg * K + k0 + c * 8);
        float4 lo4 = src[0], hi4 = src[1];
        unsigned q0 = pack_bf16x2(lo4.x, lo4.y);
        unsigned q1 = pack_bf16x2(lo4.z, lo4.w);
        unsigned q2 = pack_bf16x2(hi4.x, hi4.y);
        unsigned q3 = pack_bf16x2(hi4.z, hi4.w);
        int off = m * 128 + ((c * 16) ^ ((m & 7) << 4));
        *(int4*)(As + off) = make_int4(q0, q1, q2, q3);
      }
    } else {
      const unsigned short* A = (const unsigned short*)Ain;
#pragma unroll
      for (int it = 0; it < 4; ++it) {
        int u = it * 256 + tid;
        int m = u >> 3, c = u & 7;
        int mg = bm + m; if (mg >= M) mg = M - 1;
        int4 v = *(const int4*)((const char*)(A + (size_t)mg * K + k0) + c * 16);
        int off = m * 128 + ((c * 16) ^ ((m & 7) << 4));
        *(int4*)(As + off) = v;
      }
    }
#pragma unroll
    for (int it = 0; it < 4; ++it) {
      int u = it * 256 + tid;
      int n = u >> 3, c = u & 7;
      int4 v = *(const int4*)((const char*)(Bt + (size_t)(bn + n) * ldB + k0) + c * 16);
      int off = n * 128 + ((c * 16) ^ ((n & 7) << 4));
      *(int4*)(Bs + off) = v;
    }
    __syncthreads();
#pragma unroll
    for (int kk = 0; kk < 2; ++kk) {
      int kbyte = kk * 64 + ((lane >> 4) << 4);
      short8 af[2];
#pragma unroll
      for (int mi = 0; mi < 2; ++mi) {
        int m = wv * 32 + mi * 16 + (lane & 15);
        af[mi] = *(const short8*)(As + m * 128 + (kbyte ^ ((m & 7) << 4)));
      }
#pragma unroll
      for (int ni = 0; ni < 8; ++ni) {
        int n = ni * 16 + (lane & 15);
        short8 bf = *(const short8*)(Bs + n * 128 + (kbyte ^ ((n & 7) << 4)));
#pragma unroll
        for (int mi = 0; mi < 2; ++mi)
          acc[mi][ni] = __builtin_amdgcn_mfma_f32_16x16x32_bf16(af[mi], bf, acc[mi][ni], 0, 0, 0);
      }
    }
    __syncthreads();
  }
#pragma unroll
  for (int mi = 0; mi < 2; ++mi) {
#pragma unroll
    for (int r = 0; r < 4; ++r) {
      int row = bm + wv * 32 + mi * 16 + ((lane >> 4) << 2) + r;
      if (row < M) {
#pragma unroll
        for (int ni = 0; ni < 8; ++ni) {
          int col = bn + ni * 16 + (lane & 15);
          if (col < Nstore) {
            float v = acc[mi][ni][r] + (bias ? bias[col] : 0.f);
            if (RELU_OUT) v = fmaxf(v, 0.f);
            if (OUT_BF16)
              ((unsigned short*)Cv)[(size_t)row * ldC + col] = f32_to_bf16_bits(v);
            else
              ((float*)Cv)[(size_t)row * ldC + col] = v;
          }
        }
      }
    }
  }
}

// ================= unified projection GEMM (5 segments, one dispatch) ==============
struct ProjP {
  const float *A0, *A1, *A2, *A3, *A4;
  const float *b0, *b1, *b2, *b3, *b4;
  int t1, t2, t3, t4;   // tile starts of segments 1..4
};

__global__ __launch_bounds__(256) void proj_all(ProjP P, const unsigned short* __restrict__ Wp,
                                                unsigned short* __restrict__ x_all) {
  __shared__ char As[128 * 128];
  __shared__ char Bs[128 * 128];
  const int by = blockIdx.y;
  const int tid = threadIdx.x;
  const int lane = tid & 63;
  const int wv = tid >> 6;
  const float* A; const float* bias;
  int M, K, Woff, tile0; long Coff;
  if (by < P.t1)      { A = P.A0; bias = P.b0; M = NU;    K = 256; Woff = 0;      Coff = 0;                 tile0 = 0; }
  else if (by < P.t2) { A = P.A1; bias = P.b1; M = NFOOD; K = 512; Woff = 32768;  Coff = (long)NU * 128;    tile0 = P.t1; }
  else if (by < P.t3) { A = P.A2; bias = P.b2; M = NING;  K = 128; Woff = 98304;  Coff = (long)(NU+NFOOD)*128; tile0 = P.t2; }
  else if (by < P.t4) { A = P.A3; bias = P.b3; M = NCAT;  K = 64;  Woff = 114688; Coff = (long)(NU+NFOOD+NING)*128; tile0 = P.t3; }
  else                { A = P.A4; bias = P.b4; M = NHAB;  K = 64;  Woff = 122880; Coff = (long)(NU+NFOOD+NING+NCAT)*128; tile0 = P.t4; }
  const unsigned short* Bt = Wp + Woff;
  const int bm = (by - tile0) * 128;
  f32x4 acc[2][8] = {};

  for (int k0 = 0; k0 < K; k0 += 64) {
#pragma unroll
    for (int it = 0; it < 4; ++it) {
      int u = it * 256 + tid;
      int m = u >> 3, c = u & 7;
      int mg = bm + m; if (mg >= M) mg = M - 1;
      const float4* src = (const float4*)(A + (size_t)mg * K + k0 + c * 8);
      float4 lo4 = src[0], hi4 = src[1];
      unsigned q0 = pack_bf16x2(lo4.x, lo4.y);
      unsigned q1 = pack_bf16x2(lo4.z, lo4.w);
      unsigned q2 = pack_bf16x2(hi4.x, hi4.y);
      unsigned q3 = pack_bf16x2(hi4.z, hi4.w);
      int off = m * 128 + ((c * 16) ^ ((m & 7) << 4));
      *(int4*)(As + off) = make_int4(q0, q1, q2, q3);
    }
#pragma unroll
    for (int it = 0; it < 4; ++it) {
      int u = it * 256 + tid;
      int n = u >> 3, c = u & 7;
      int4 v = *(const int4*)((const char*)(Bt + (size_t)n * K + k0) + c * 16);
      int off = n * 128 + ((c * 16) ^ ((n & 7) << 4));
      *(int4*)(Bs + off) = v;
    }
    __syncthreads();
#pragma unroll
    for (int kk = 0; kk < 2; ++kk) {
      int kbyte = kk * 64 + ((lane >> 4) << 4);
      short8 af[2];
#pragma unroll
      for (int mi = 0; mi < 2; ++mi) {
        int m = wv * 32 + mi * 16 + (lane & 15);
        af[mi] = *(const short8*)(As + m * 128 + (kbyte ^ ((m & 7) << 4)));
      }
#pragma unroll
      for (int ni = 0; ni < 8; ++ni) {
        int n = ni * 16 + (lane & 15);
        short8 bf = *(const short8*)(Bs + n * 128 + (kbyte ^ ((n & 7) << 4)));
#pragma unroll
        for (int mi = 0; mi < 2; ++mi)
          acc[mi][ni] = __builtin_amdgcn_mfma_f32_16x16x32_bf16(af[mi], bf, acc[mi][ni], 0, 0, 0);
      }
    }
    __syncthreads();
  }
#pragma unroll
  for (int mi = 0; mi < 2; ++mi) {
#pragma unroll
    for (int r = 0; r < 4; ++r) {
      int row = bm + wv * 32 + mi * 16 + ((lane >> 4) << 2) + r;
      if (row < M) {
#pragma unroll
        for (int ni = 0; ni < 8; ++ni) {
          int col = ni * 16 + (lane & 15);
          float v = acc[mi][ni][r] + bias[col];
          x_all[Coff + (size_t)row * 128 + col] = f32_to_bf16_bits(v);
        }
      }
    }
  }
}

// ================= layer-1 GEMM: A = [M9 (1024 cols) | x_all rows] =================
__global__ __launch_bounds__(256) void l1_gemm(
    const unsigned short* __restrict__ M9, const unsigned short* __restrict__ xall,
    const unsigned short* __restrict__ W1rT, const float* __restrict__ b1,
    unsigned short* __restrict__ x1, int d0, int Mc) {
  __shared__ char As[128 * 128];
  __shared__ char Bs[128 * 128];
  const int tid = threadIdx.x;
  const int lane = tid & 63;
  const int wv = tid >> 6;
  const int bm = blockIdx.y * 128;
  f32x4 acc[2][8] = {};

  for (int k0 = 0; k0 < 1152; k0 += 64) {
#pragma unroll
    for (int it = 0; it < 4; ++it) {
      int u = it * 256 + tid;
      int m = u >> 3, c = u & 7;
      int mg = bm + m; if (mg >= Mc) mg = Mc - 1;
      const char* src;
      if (k0 < 1024) src = (const char*)(M9 + (size_t)mg * 1024 + k0) + c * 16;
      else src = (const char*)(xall + (size_t)(d0 + mg) * 128 + (k0 - 1024)) + c * 16;
      int4 v = *(const int4*)src;
      int off = m * 128 + ((c * 16) ^ ((m & 7) << 4));
      *(int4*)(As + off) = v;
    }
#pragma unroll
    for (int it = 0; it < 4; ++it) {
      int u = it * 256 + tid;
      int n = u >> 3, c = u & 7;
      int4 v = *(const int4*)((const char*)(W1rT + (size_t)n * 1152 + k0) + c * 16);
      int off = n * 128 + ((c * 16) ^ ((n & 7) << 4));
      *(int4*)(Bs + off) = v;
    }
    __syncthreads();
#pragma unroll
    for (int kk = 0; kk < 2; ++kk) {
      int kbyte = kk * 64 + ((lane >> 4) << 4);
      short8 af[2];
#pragma unroll
      for (int mi = 0; mi < 2; ++mi) {
        int m = wv * 32 + mi * 16 + (lane & 15);
        af[mi] = *(const short8*)(As + m * 128 + (kbyte ^ ((m & 7) << 4)));
      }
#pragma unroll
      for (int ni = 0; ni < 8; ++ni) {
        int n = ni * 16 + (lane & 15);
        short8 bf = *(const short8*)(Bs + n * 128 + (kbyte ^ ((n & 7) << 4)));
#pragma unroll
        for (int mi = 0; mi < 2; ++mi)
          acc[mi][ni] = __builtin_amdgcn_mfma_f32_16x16x32_bf16(af[mi], bf, acc[mi][ni], 0, 0, 0);
      }
    }
    __syncthreads();
  }
#pragma unroll
  for (int mi = 0; mi < 2; ++mi) {
#pragma unroll
    for (int r = 0; r < 4; ++r) {
      int row = bm + wv * 32 + mi * 16 + ((lane >> 4) << 2) + r;
      if (row < Mc) {
#pragma unroll
        for (int ni = 0; ni < 8; ++ni) {
          int col = ni * 16 + (lane & 15);
          float v = fmaxf(acc[mi][ni][r] + b1[col], 0.f);
          x1[(size_t)(d0 + row) * 128 + col] = f32_to_bf16_bits(v);
        }
      }
    }
  }
}

// ============ unified weight repack + cnt_dt zeroing (one dispatch) ================
__global__ void build_all(const float* __restrict__ Wu, const float* __restrict__ Wf,
                          const float* __restrict__ Wi, const float* __restrict__ Wc,
                          const float* __restrict__ Wh, const float* __restrict__ W1,
                          const float* __restrict__ root1, const float* __restrict__ W2,
                          const float* __restrict__ root2,
                          unsigned short* __restrict__ Wp,
                          unsigned short* __restrict__ W1rT,
                          unsigned short* __restrict__ B2pad,
                          int* __restrict__ cnt_dt) {
  const int T0 = 32768, T1 = T0 + 65536, T2 = T1 + 16384, T3 = T2 + 8192, T4 = T3 + 8192,
            T5 = T4 + 147456, T6 = T5 + 16384, T7 = T6 + NSEG;
  int i = blockIdx.x * blockDim.x + threadIdx.x;
  int stride = gridDim.x * blockDim.x;
  for (; i < T7; i += stride) {
    if (i < T0) {                       // WuT [128][256]
      int n = i / 256, k = i - n * 256;
      Wp[i] = f32_to_bf16_bits(Wu[(size_t)k * 128 + n]);
    } else if (i < T1) {                // WfT [128][512]
      int j = i - T0; int n = j / 512, k = j - n * 512;
      Wp[i] = f32_to_bf16_bits(Wf[(size_t)k * 128 + n]);
    } else if (i < T2) {                // WiT [128][128]
      int j = i - T1; int n = j >> 7, k = j & 127;
      Wp[i] = f32_to_bf16_bits(Wi[(size_t)k * 128 + n]);
    } else if (i < T3) {                // WcT [128][64]
      int j = i - T2; int n = j >> 6, k = j & 63;
      Wp[i] = f32_to_bf16_bits(Wc[(size_t)k * 128 + n]);
    } else if (i < T4) {                // WhT [128][64]
      int j = i - T3; int n = j >> 6, k = j & 63;
      Wp[i] = f32_to_bf16_bits(Wh[(size_t)k * 128 + n]);
    } else if (i < T5) {                // W1rT [128][1152]
      int j = i - T4; int f = j / 1152, c = j - f * 1152;
      float v;
      if (c < 1024) { int t = c >> 7, k = c & 127; v = W1[((size_t)t * 128 + k) * 128 + f]; }
      else { int k = c - 1024; v = root1[(size_t)k * 128 + f]; }
      W1rT[j] = f32_to_bf16_bits(v);
    } else if (i < T6) {                // B2pad [128][128]
      int j = i - T5; int n = j >> 7, k = j & 127;
      float v = 0.f;
      if (n < 16) v = W2[((size_t)(n >> 1) * 128 + k) * 2 + (n & 1)];
      else if (n < 18) v = root2[(size_t)k * 2 + (n - 16)];
      B2pad[j] = f32_to_bf16_bits(v);
    } else {                            // zero cnt_dt
      cnt_dt[i - T6] = 0;
    }
  }
}

// ========== CSR build keyed by (dst, rel), XCD-partitioned by dst chunk ===========
__global__ void count_dt_xcd(const int* __restrict__ ei, const int* __restrict__ et,
                             int* __restrict__ cnt_dt) {
  int cls = blockIdx.x & 7;
  unsigned lo = cls * NCHUNK, hi = lo + NCHUNK;
  int e = (blockIdx.x >> 3) * blockDim.x + threadIdx.x;
  int stride = (gridDim.x >> 3) * blockDim.x;
  for (; e < NEDGE; e += stride) {
    unsigned d = (unsigned)ei[NEDGE + e]; if (d >= NNODES) d = 0;
    if (d < lo || d >= hi) continue;
    unsigned t = (unsigned)et[e]; if (t >= NREL) t = 0;
    atomicAdd(cnt_dt + d * NREL + t, 1);
  }
}

__global__ void scan_block(const int* __restrict__ in, int* __restrict__ out,
                           int* __restrict__ bsum, int n) {
  __shared__ int s[SCAN_B];
  int i = blockIdx.x * SCAN_B + threadIdx.x;
  int x = (i < n) ? in[i] : 0;
  s[threadIdx.x] = x;
  __syncthreads();
  for (int d = 1; d < SCAN_B; d <<= 1) {
    int v = (threadIdx.x >= d) ? s[threadIdx.x - d] : 0;
    __syncthreads();
    s[threadIdx.x] += v;
    __syncthreads();
  }
  if (i < n) out[i] = s[threadIdx.x] - x;
  if (threadIdx.x == SCAN_B - 1) bsum[blockIdx.x] = s[threadIdx.x];
}

// single-block exclusive scan over nb block sums (carry-chained chunks of 256)
__global__ void scan_mid(const int* __restrict__ bsumA, int* __restrict__ bsumAs, int nb) {
  __shared__ int s[256];
  __shared__ int carry;
  if (threadIdx.x == 0) carry = 0;
  __syncthreads();
  for (int c0 = 0; c0 < nb; c0 += 256) {
    int i = c0 + threadIdx.x;
    int x = (i < nb) ? bsumA[i] : 0;
    s[threadIdx.x] = x;
    __syncthreads();
    for (int d = 1; d < 256; d <<= 1) {
      int v = (threadIdx.x >= d) ? s[threadIdx.x - d] : 0;
      __syncthreads();
      s[threadIdx.x] += v;
      __syncthreads();
    }
    if (i < nb) bsumAs[i] = carry + s[threadIdx.x] - x;
    __syncthreads();
    if (threadIdx.x == 255) carry += s[255];
    __syncthreads();
  }
}

__global__ void scan_apply2(int* __restrict__ rp2, const int* __restrict__ lvl1,
                            int* __restrict__ slot, int n) {
  int i = blockIdx.x * blockDim.x + threadIdx.x;
  if (i >= n) return;
  int v = rp2[i] + lvl1[i >> 8];
  rp2[i] = v;
  slot[i] = v;
}

__global__ void scatter_edges_xcd(const int* __restrict__ ei, const int* __restrict__ et,
                                  int* __restrict__ slot, unsigned* __restrict__ packed) {
  int cls = blockIdx.x & 7;
  unsigned lo = cls * NCHUNK, hi = lo + NCHUNK;
  int e = (blockIdx.x >> 3) * blockDim.x + threadIdx.x;
  int stride = (gridDim.x >> 3) * blockDim.x;
  for (; e < NEDGE; e += stride) {
    unsigned d = (unsigned)ei[NEDGE + e]; if (d >= NNODES) d = 0;
    if (d < lo || d >= hi) continue;
    unsigned s = (unsigned)ei[e];  if (s >= NNODES) s = 0;
    unsigned t = (unsigned)et[e];  if (t >= NREL)  t = 0;
    int pos = atomicAdd(slot + d * NREL + t, 1);
    packed[pos] = s;
  }
}

// ===== layer-1 gather-means: 4 dsts/wave (16-lane quarters), 8-rel rounds ==========
__global__ __launch_bounds__(256) void gather_rounds(
    const int* __restrict__ rp2, const unsigned* __restrict__ packed,
    const int4* __restrict__ xu, unsigned* __restrict__ M9, int d0, int d1) {
  const int lane = threadIdx.x & 63;
  const int qtr = lane >> 4;
  const int sub = lane & 15;
  int wid = (blockIdx.x * blockDim.x + threadIdx.x) >> 6;
  int nw = (gridDim.x * blockDim.x) >> 6;
  for (int p0 = d0 + wid * 4; p0 < d1; p0 += nw * 4) {
    int d = p0 + qtr;
    bool valid = (d < d1);
    int bi = (valid ? d : d0) * NREL;
    int b[9];
#pragma unroll
    for (int q = 0; q < 9; ++q)
      b[q] = (bi + q == NSEG) ? NEDGE : rp2[bi + q];
    int len[8];
    int mx = 0;
#pragma unroll
    for (int q = 0; q < 8; ++q) {
      len[q] = valid ? (b[q + 1] - b[q]) : 0;
      mx = len[q] > mx ? len[q] : mx;
    }
    float a[8][8];
#pragma unroll
    for (int q = 0; q < 8; ++q)
#pragma unroll
      for (int j = 0; j < 8; ++j) a[q][j] = 0.f;
    for (int r = 0; r < mx; ++r) {
#pragma unroll
      for (int q = 0; q < 8; ++q) {
        if (r < len[q]) {
          int4 v = xu[(size_t)packed[b[q] + r] * 16 + sub];
          unsigned u0 = (unsigned)v.x, u1 = (unsigned)v.y;
          unsigned u2 = (unsigned)v.z, u3 = (unsigned)v.w;
          a[q][0] += bf16_bits_to_f32((unsigned short)(u0 & 0xffffu));
          a[q][1] += bf16_bits_to_f32((unsigned short)(u0 >> 16));
          a[q][2] += bf16_bits_to_f32((unsigned short)(u1 & 0xffffu));
          a[q][3] += bf16_bits_to_f32((unsigned short)(u1 >> 16));
          a[q][4] += bf16_bits_to_f32((unsigned short)(u2 & 0xffffu));
          a[q][5] += bf16_bits_to_f32((unsigned short)(u2 >> 16));
          a[q][6] += bf16_bits_to_f32((unsigned short)(u3 & 0xffffu));
          a[q][7] += bf16_bits_to_f32((unsigned short)(u3 >> 16));
        }
      }
    }
    if (valid) {
      unsigned* rowp = M9 + (size_t)(d - d0) * 512;
#pragma unroll
      for (int q = 0; q < 8; ++q) {
        float w = 1.0f / (float)(len[q] > 0 ? len[q] : 1);
        uint4 o;
        o.x = pack_bf16x2(a[q][0] * w, a[q][1] * w);
        o.y = pack_bf16x2(a[q][2] * w, a[q][3] * w);
        o.z = pack_bf16x2(a[q][4] * w, a[q][5] * w);
        o.w = pack_bf16x2(a[q][6] * w, a[q][7] * w);
        *(uint4*)(rowp + q * 64 + sub * 4) = o;
      }
    }
  }
}

// ===== layer-2 aggregation + log_softmax (4 lanes/dst; lane owns 2 relations) ======
__global__ void fused_out(const int* __restrict__ rp2, const unsigned* __restrict__ packed,
                          const float* __restrict__ h2, const float* __restrict__ b2,
                          float* __restrict__ out) {
  int gt = blockIdx.x * blockDim.x + threadIdx.x;
  int d = gt >> 2;
  int l4 = gt & 3;
  if (d >= NNODES) return;
  float z0 = 0.f, z1 = 0.f;
#pragma unroll
  for (int k = 0; k < 2; ++k) {
    int t = l4 * 2 + k;
    int i = d * NREL + t;
    int beg = rp2[i];
    int end = (i == NSEG - 1) ? NEDGE : rp2[i + 1];
    float s0 = 0.f, s1 = 0.f;
    for (int e = beg; e < end; ++e) {
      unsigned s = packed[e];
      s0 += h2[(size_t)s * 18 + t * 2];
      s1 += h2[(size_t)s * 18 + t * 2 + 1];
    }
    int c = end - beg;
    float w = 1.0f / (float)(c > 0 ? c : 1);
    z0 += s0 * w;
    z1 += s1 * w;
  }
  z0 += __shfl_xor(z0, 1, 4); z0 += __shfl_xor(z0, 2, 4);
  z1 += __shfl_xor(z1, 1, 4); z1 += __shfl_xor(z1, 2, 4);
  if (l4 == 0) {
    z0 += h2[(size_t)d * 18 + 16] + b2[0];
    z1 += h2[(size_t)d * 18 + 17] + b2[1];
    float m = fmaxf(z0, z1);
    float l = m + logf(expf(z0 - m) + expf(z1 - m));
    out[(size_t)d * 2 + 0] = z0 - l;
    out[(size_t)d * 2 + 1] = z1 - l;
  }
}

__global__ void fill_sentinel(float* __restrict__ out, int n, float v) {
  int i = blockIdx.x * blockDim.x + threadIdx.x;
  if (i < n) out[i] = v;
}

// ===================================================================================
extern "C" void kernel_launch(void* const* d_in, const int* in_sizes, int n_in,
                              void* d_out, int out_size, void* d_ws, size_t ws_size,
                              hipStream_t stream) {
  const float* x_user = (const float*)d_in[0];
  const float* x_food = (const float*)d_in[1];
  const float* x_ing  = (const float*)d_in[2];
  const float* x_cat  = (const float*)d_in[3];
  const float* x_hab  = (const float*)d_in[4];
  const float* Wu = (const float*)d_in[5];  const float* bu  = (const float*)d_in[6];
  const float* Wf = (const float*)d_in[7];  const float* bfo = (const float*)d_in[8];
  const float* Wi = (const float*)d_in[9];  const float* bi  = (const float*)d_in[10];
  const float* Wc = (const float*)d_in[11]; const float* bc  = (const float*)d_in[12];
  const float* Wh = (const float*)d_in[13]; const float* bh  = (const float*)d_in[14];
  const float* W1 = (const float*)d_in[15]; const float* root1 = (const float*)d_in[16];
  const float* b1 = (const float*)d_in[17];
  const float* W2 = (const float*)d_in[18]; const float* root2 = (const float*)d_in[19];
  const float* b2 = (const float*)d_in[20];
  const int* ei = (const int*)d_in[21];
  const int* et = (const int*)d_in[22];
  (void)in_sizes; (void)n_in;

  dim3 blk(256);
  const int NB_A = (NSEG + SCAN_B - 1) / SCAN_B;   // 3594

  // ---- base layout ----
  char* ws = (char*)d_ws;
  size_t off = 0;
  unsigned short* x_all = (unsigned short*)(ws + off); off += alignup((size_t)NNODES * 128 * 2);
  unsigned short* x1    = (unsigned short*)(ws + off); off += alignup((size_t)NNODES * 128 * 2);
  int* cnt_dt = (int*)(ws + off);        off += alignup((size_t)NSEG * 4);
  int* rp2 = (int*)(ws + off);           off += alignup((size_t)NSEG * 4);
  int* slot = (int*)(ws + off);          off += alignup((size_t)NSEG * 4);
  unsigned* packed = (unsigned*)(ws + off); off += alignup((size_t)NEDGE * 4);
  int* bsumA = (int*)(ws + off);         off += alignup((size_t)4096 * 4);
  int* bsumAs = (int*)(ws + off);        off += alignup((size_t)4096 * 4);
  unsigned short* Wp = (unsigned short*)(ws + off);   off += alignup((size_t)131072 * 2);
  unsigned short* W1rT = (unsigned short*)(ws + off); off += alignup((size_t)128 * 1152 * 2);
  unsigned short* B2pad = (unsigned short*)(ws + off); off += alignup((size_t)128 * 128 * 2);
  float* h2 = (float*)(ws + off);        off += alignup((size_t)NNODES * 18 * 4);
  size_t base = off;

  // pick smallest chunk count whose M9 buffer (1024 cols) fits
  int NCH = 0;
  for (int cand = 1; cand <= 16; cand <<= 1) {
    size_t ch = ((size_t)NNODES + cand - 1) / cand;
    if (base + alignup(ch * 1024 * 2) <= ws_size) { NCH = cand; break; }
  }
  if (NCH == 0) {
    fill_sentinel<<<(out_size + 255) / 256, blk, 0, stream>>>((float*)d_out, out_size, -777.0f);
    return;
  }
  unsigned short* M9 = (unsigned short*)(ws + base);
  const int CH = (NNODES + NCH - 1) / NCH;

  // ---- weight repacks + cnt_dt zero (1 dispatch) ----
  build_all<<<2048, blk, 0, stream>>>(Wu, Wf, Wi, Wc, Wh, W1, root1, W2, root2,
                                      Wp, W1rT, B2pad, cnt_dt);

  // ---- projections -> x_all (1 dispatch, 902 tiles) ----
  {
    ProjP P;
    P.A0 = x_user; P.A1 = x_food; P.A2 = x_ing; P.A3 = x_cat; P.A4 = x_hab;
    P.b0 = bu; P.b1 = bfo; P.b2 = bi; P.b3 = bc; P.b4 = bh;
    P.t1 = 391; P.t2 = 391 + 235; P.t3 = 391 + 235 + 157; P.t4 = 391 + 235 + 157 + 40;
    int ntiles = P.t4 + 79;   // 902
    proj_all<<<dim3(1, ntiles), blk, 0, stream>>>(P, Wp, x_all);
  }

  // ---- (dst,rel)-keyed CSR build (XCD-partitioned) ----
  count_dt_xcd<<<2048, blk, 0, stream>>>(ei, et, cnt_dt);
  scan_block<<<NB_A, SCAN_B, 0, stream>>>(cnt_dt, rp2, bsumA, NSEG);
  scan_mid<<<1, 256, 0, stream>>>(bsumA, bsumAs, NB_A);
  scan_apply2<<<NB_A, SCAN_B, 0, stream>>>(rp2, bsumAs, slot, NSEG);
  scatter_edges_xcd<<<2048, blk, 0, stream>>>(ei, et, slot, packed);

  // ---- layer 1: per dst-chunk, load-balanced gather + K=1152 GEMM -> x1 ----
  for (int c = 0; c < NCH; ++c) {
    int d0 = c * CH;
    int d1 = (d0 + CH < NNODES) ? d0 + CH : NNODES;
    int Mc = d1 - d0;
    int groups = (Mc + 3) / 4;
    int gblocks = (groups + 3) / 4;   // 4 waves per block, 1 group per wave
    gather_rounds<<<gblocks, blk, 0, stream>>>(rp2, packed, (const int4*)x_all,
                                               (unsigned*)M9, d0, d1);
    dim3 g(1, (Mc + 127) / 128);
    l1_gemm<<<g, blk, 0, stream>>>(M9, x_all, W1rT, b1, x1, d0, Mc);
  }

  // ---- layer 2: h2 = x1 @ B2pad (store 18 cols) ----
  { dim3 g(1, (NNODES + 127) / 128);
    mfma_gemm<false, false, false><<<g, blk, 0, stream>>>(x1, B2pad, 128, nullptr, (void*)h2, 18, 18, NNODES, 128, 128); }

  fused_out<<<(NNODES * 4 + 255) / 256, blk, 0, stream>>>(rp2, packed, h2, b2, (float*)d_out);
}

// Round 16
// 457.128 us; speedup vs baseline: 1.0487x; 1.0487x over previous
//
#include <hip/hip_runtime.h>
#include <hip/hip_bf16.h>
#include <math.h>

#define NU 50000
#define NFOOD 30000
#define NING 20000
#define NCAT 5000
#define NHAB 10000
#define NNODES 115000
#define NCHUNK 14375   // NNODES/8 (XCD dst partition)
#define NREL 8
#define NSEG (NNODES * NREL)   // 920000
#define NEDGE 1500000
#define SCAN_B 256

typedef __attribute__((ext_vector_type(8))) short short8;
typedef __attribute__((ext_vector_type(4))) float f32x4;

static inline size_t alignup(size_t x) { return (x + 255) & ~(size_t)255; }

__device__ inline float bf16_bits_to_f32(unsigned short u) {
  return __uint_as_float(((unsigned)u) << 16);
}
__device__ inline unsigned short f32_to_bf16_bits(float f) {
  unsigned u = __float_as_uint(f);
  unsigned r = u + 0x7fffu + ((u >> 16) & 1u);
  return (unsigned short)(r >> 16);
}
__device__ inline unsigned pack_bf16x2(float lo, float hi) {
  return (unsigned)f32_to_bf16_bits(lo) | ((unsigned)f32_to_bf16_bits(hi) << 16);
}

// ================= unified projection GEMM (5 segments, one dispatch) ==============
struct ProjP {
  const float *A0, *A1, *A2, *A3, *A4;
  const float *b0, *b1, *b2, *b3, *b4;
  int t1, t2, t3, t4;   // tile starts of segments 1..4
};

__global__ __launch_bounds__(256) void proj_all(ProjP P, const unsigned short* __restrict__ Wp,
                                                unsigned short* __restrict__ x_all) {
  __shared__ char As[128 * 128];
  __shared__ char Bs[128 * 128];
  const int by = blockIdx.y;
  const int tid = threadIdx.x;
  const int lane = tid & 63;
  const int wv = tid >> 6;
  const float* A; const float* bias;
  int M, K, Woff, tile0; long Coff;
  if (by < P.t1)      { A = P.A0; bias = P.b0; M = NU;    K = 256; Woff = 0;      Coff = 0;                 tile0 = 0; }
  else if (by < P.t2) { A = P.A1; bias = P.b1; M = NFOOD; K = 512; Woff = 32768;  Coff = (long)NU * 128;    tile0 = P.t1; }
  else if (by < P.t3) { A = P.A2; bias = P.b2; M = NING;  K = 128; Woff = 98304;  Coff = (long)(NU+NFOOD)*128; tile0 = P.t2; }
  else if (by < P.t4) { A = P.A3; bias = P.b3; M = NCAT;  K = 64;  Woff = 114688; Coff = (long)(NU+NFOOD+NING)*128; tile0 = P.t3; }
  else                { A = P.A4; bias = P.b4; M = NHAB;  K = 64;  Woff = 122880; Coff = (long)(NU+NFOOD+NING+NCAT)*128; tile0 = P.t4; }
  const unsigned short* Bt = Wp + Woff;
  const int bm = (by - tile0) * 128;
  f32x4 acc[2][8] = {};

  for (int k0 = 0; k0 < K; k0 += 64) {
#pragma unroll
    for (int it = 0; it < 4; ++it) {
      int u = it * 256 + tid;
      int m = u >> 3, c = u & 7;
      int mg = bm + m; if (mg >= M) mg = M - 1;
      const float4* src = (const float4*)(A + (size_t)mg * K + k0 + c * 8);
      float4 lo4 = src[0], hi4 = src[1];
      unsigned q0 = pack_bf16x2(lo4.x, lo4.y);
      unsigned q1 = pack_bf16x2(lo4.z, lo4.w);
      unsigned q2 = pack_bf16x2(hi4.x, hi4.y);
      unsigned q3 = pack_bf16x2(hi4.z, hi4.w);
      int off = m * 128 + ((c * 16) ^ ((m & 7) << 4));
      *(int4*)(As + off) = make_int4(q0, q1, q2, q3);
    }
#pragma unroll
    for (int it = 0; it < 4; ++it) {
      int u = it * 256 + tid;
      int n = u >> 3, c = u & 7;
      int4 v = *(const int4*)((const char*)(Bt + (size_t)n * K + k0) + c * 16);
      int off = n * 128 + ((c * 16) ^ ((n & 7) << 4));
      *(int4*)(Bs + off) = v;
    }
    __syncthreads();
#pragma unroll
    for (int kk = 0; kk < 2; ++kk) {
      int kbyte = kk * 64 + ((lane >> 4) << 4);
      short8 af[2];
#pragma unroll
      for (int mi = 0; mi < 2; ++mi) {
        int m = wv * 32 + mi * 16 + (lane & 15);
        af[mi] = *(const short8*)(As + m * 128 + (kbyte ^ ((m & 7) << 4)));
      }
#pragma unroll
      for (int ni = 0; ni < 8; ++ni) {
        int n = ni * 16 + (lane & 15);
        short8 bf = *(const short8*)(Bs + n * 128 + (kbyte ^ ((n & 7) << 4)));
#pragma unroll
        for (int mi = 0; mi < 2; ++mi)
          acc[mi][ni] = __builtin_amdgcn_mfma_f32_16x16x32_bf16(af[mi], bf, acc[mi][ni], 0, 0, 0);
      }
    }
    __syncthreads();
  }
#pragma unroll
  for (int mi = 0; mi < 2; ++mi) {
#pragma unroll
    for (int r = 0; r < 4; ++r) {
      int row = bm + wv * 32 + mi * 16 + ((lane >> 4) << 2) + r;
      if (row < M) {
#pragma unroll
        for (int ni = 0; ni < 8; ++ni) {
          int col = ni * 16 + (lane & 15);
          float v = acc[mi][ni][r] + bias[col];
          x_all[Coff + (size_t)row * 128 + col] = f32_to_bf16_bits(v);
        }
      }
    }
  }
}

// ====== layer-1 GEMM + fused layer-2: h2 = relu(concat(M9,x_all)@W1rT + b1) @ B2pad =
// A = [M9 (1024 cols) | x_all rows], K=1152, N=128. x1 tile kept in LDS (bf16),
// then 16 MFMA vs B2pad (rows 0..31) produce h2 (18 cols). No x1 global buffer.
__global__ __launch_bounds__(256) void l1_gemm(
    const unsigned short* __restrict__ M9, const unsigned short* __restrict__ xall,
    const unsigned short* __restrict__ W1rT, const float* __restrict__ b1,
    const unsigned short* __restrict__ B2pad, float* __restrict__ h2,
    int d0, int Mc) {
  __shared__ char As[128 * 128];
  __shared__ char Bs[128 * 128];
  __shared__ char B2s[32 * 256];
  const int tid = threadIdx.x;
  const int lane = tid & 63;
  const int wv = tid >> 6;
  const int r16 = lane & 15;
  const int q0 = lane >> 4;
  const int bm = blockIdx.y * 128;
  f32x4 acc[2][8] = {};

  // stage B2pad rows 0..31 (swizzled); consumed only after later barriers
  for (int i = tid; i < 512; i += 256) {
    int n = i >> 4, g = i & 15;
    int4 v = *(const int4*)((const char*)(B2pad + (size_t)n * 128) + g * 16);
    *(int4*)(B2s + n * 256 + ((g * 16) ^ ((n & 7) << 4))) = v;
  }

  for (int k0 = 0; k0 < 1152; k0 += 64) {
#pragma unroll
    for (int it = 0; it < 4; ++it) {
      int u = it * 256 + tid;
      int m = u >> 3, c = u & 7;
      int mg = bm + m; if (mg >= Mc) mg = Mc - 1;
      const char* src;
      if (k0 < 1024) src = (const char*)(M9 + (size_t)mg * 1024 + k0) + c * 16;
      else src = (const char*)(xall + (size_t)(d0 + mg) * 128 + (k0 - 1024)) + c * 16;
      int4 v = *(const int4*)src;
      int off = m * 128 + ((c * 16) ^ ((m & 7) << 4));
      *(int4*)(As + off) = v;
    }
#pragma unroll
    for (int it = 0; it < 4; ++it) {
      int u = it * 256 + tid;
      int n = u >> 3, c = u & 7;
      int4 v = *(const int4*)((const char*)(W1rT + (size_t)n * 1152 + k0) + c * 16);
      int off = n * 128 + ((c * 16) ^ ((n & 7) << 4));
      *(int4*)(Bs + off) = v;
    }
    __syncthreads();
#pragma unroll
    for (int kk = 0; kk < 2; ++kk) {
      int kbyte = kk * 64 + (q0 << 4);
      short8 af[2];
#pragma unroll
      for (int mi = 0; mi < 2; ++mi) {
        int m = wv * 32 + mi * 16 + r16;
        af[mi] = *(const short8*)(As + m * 128 + (kbyte ^ ((m & 7) << 4)));
      }
#pragma unroll
      for (int ni = 0; ni < 8; ++ni) {
        int n = ni * 16 + r16;
        short8 bf = *(const short8*)(Bs + n * 128 + (kbyte ^ ((n & 7) << 4)));
#pragma unroll
        for (int mi = 0; mi < 2; ++mi)
          acc[mi][ni] = __builtin_amdgcn_mfma_f32_16x16x32_bf16(af[mi], bf, acc[mi][ni], 0, 0, 0);
      }
    }
    __syncthreads();
  }

  // ---- x1 tile (bf16, relu) into As (rows 0..63) / Bs (rows 64..127), swizzled ----
#pragma unroll
  for (int mi = 0; mi < 2; ++mi) {
#pragma unroll
    for (int r = 0; r < 4; ++r) {
      int row = wv * 32 + mi * 16 + q0 * 4 + r;   // local 0..127
      char* base = (row < 64) ? As : Bs;
      int rb = (row & 63) * 256;
#pragma unroll
      for (int ni = 0; ni < 8; ++ni) {
        int col = ni * 16 + r16;
        float v = fmaxf(acc[mi][ni][r] + b1[col], 0.f);
        int byte = rb + ((((col >> 3) << 4) ^ ((row & 7) << 4)) | ((col & 7) << 1));
        *(unsigned short*)(base + byte) = f32_to_bf16_bits(v);
      }
    }
  }
  __syncthreads();

  // ---- layer 2: h2 tile = x1_tile @ B2pad (only 32 out cols computed, 18 stored) --
  f32x4 acc2[2][2] = {};
#pragma unroll
  for (int kk = 0; kk < 4; ++kk) {
    int kbyte = kk * 64 + (q0 << 4);
    short8 af[2];
#pragma unroll
    for (int mi = 0; mi < 2; ++mi) {
      int m = wv * 32 + mi * 16 + r16;
      const char* base = (m < 64) ? As : Bs;
      af[mi] = *(const short8*)(base + (m & 63) * 256 + (kbyte ^ ((m & 7) << 4)));
    }
#pragma unroll
    for (int ni = 0; ni < 2; ++ni) {
      int n = ni * 16 + r16;
      short8 bf = *(const short8*)(B2s + n * 256 + (kbyte ^ ((n & 7) << 4)));
#pragma unroll
      for (int mi = 0; mi < 2; ++mi)
        acc2[mi][ni] = __builtin_amdgcn_mfma_f32_16x16x32_bf16(af[mi], bf, acc2[mi][ni], 0, 0, 0);
    }
  }
#pragma unroll
  for (int mi = 0; mi < 2; ++mi) {
#pragma unroll
    for (int ni = 0; ni < 2; ++ni) {
#pragma unroll
      for (int r = 0; r < 4; ++r) {
        int row = bm + wv * 32 + mi * 16 + q0 * 4 + r;
        int col = ni * 16 + r16;
        if (row < Mc && col < 18)
          h2[(size_t)(d0 + row) * 18 + col] = acc2[mi][ni][r];
      }
    }
  }
}

// ============ unified weight repack + cnt_dt zeroing (one dispatch) ================
__global__ void build_all(const float* __restrict__ Wu, const float* __restrict__ Wf,
                          const float* __restrict__ Wi, const float* __restrict__ Wc,
                          const float* __restrict__ Wh, const float* __restrict__ W1,
                          const float* __restrict__ root1, const float* __restrict__ W2,
                          const float* __restrict__ root2,
                          unsigned short* __restrict__ Wp,
                          unsigned short* __restrict__ W1rT,
                          unsigned short* __restrict__ B2pad,
                          int* __restrict__ cnt_dt) {
  const int T0 = 32768, T1 = T0 + 65536, T2 = T1 + 16384, T3 = T2 + 8192, T4 = T3 + 8192,
            T5 = T4 + 147456, T6 = T5 + 16384, T7 = T6 + NSEG;
  int i = blockIdx.x * blockDim.x + threadIdx.x;
  int stride = gridDim.x * blockDim.x;
  for (; i < T7; i += stride) {
    if (i < T0) {                       // WuT [128][256]
      int n = i / 256, k = i - n * 256;
      Wp[i] = f32_to_bf16_bits(Wu[(size_t)k * 128 + n]);
    } else if (i < T1) {                // WfT [128][512]
      int j = i - T0; int n = j / 512, k = j - n * 512;
      Wp[i] = f32_to_bf16_bits(Wf[(size_t)k * 128 + n]);
    } else if (i < T2) {                // WiT [128][128]
      int j = i - T1; int n = j >> 7, k = j & 127;
      Wp[i] = f32_to_bf16_bits(Wi[(size_t)k * 128 + n]);
    } else if (i < T3) {                // WcT [128][64]
      int j = i - T2; int n = j >> 6, k = j & 63;
      Wp[i] = f32_to_bf16_bits(Wc[(size_t)k * 128 + n]);
    } else if (i < T4) {                // WhT [128][64]
      int j = i - T3; int n = j >> 6, k = j & 63;
      Wp[i] = f32_to_bf16_bits(Wh[(size_t)k * 128 + n]);
    } else if (i < T5) {                // W1rT [128][1152]
      int j = i - T4; int f = j / 1152, c = j - f * 1152;
      float v;
      if (c < 1024) { int t = c >> 7, k = c & 127; v = W1[((size_t)t * 128 + k) * 128 + f]; }
      else { int k = c - 1024; v = root1[(size_t)k * 128 + f]; }
      W1rT[j] = f32_to_bf16_bits(v);
    } else if (i < T6) {                // B2pad [128][128]
      int j = i - T5; int n = j >> 7, k = j & 127;
      float v = 0.f;
      if (n < 16) v = W2[((size_t)(n >> 1) * 128 + k) * 2 + (n & 1)];
      else if (n < 18) v = root2[(size_t)k * 2 + (n - 16)];
      B2pad[j] = f32_to_bf16_bits(v);
    } else {                            // zero cnt_dt
      cnt_dt[i - T6] = 0;
    }
  }
}

// ========== CSR build keyed by (dst, rel), XCD-partitioned by dst chunk ===========
__global__ void count_dt_xcd(const int* __restrict__ ei, const int* __restrict__ et,
                             int* __restrict__ cnt_dt) {
  int cls = blockIdx.x & 7;
  unsigned lo = cls * NCHUNK, hi = lo + NCHUNK;
  int e = (blockIdx.x >> 3) * blockDim.x + threadIdx.x;
  int stride = (gridDim.x >> 3) * blockDim.x;
  for (; e < NEDGE; e += stride) {
    unsigned d = (unsigned)ei[NEDGE + e]; if (d >= NNODES) d = 0;
    if (d < lo || d >= hi) continue;
    unsigned t = (unsigned)et[e]; if (t >= NREL) t = 0;
    atomicAdd(cnt_dt + d * NREL + t, 1);
  }
}

__global__ void scan_block(const int* __restrict__ in, int* __restrict__ out,
                           int* __restrict__ bsum, int n) {
  __shared__ int s[SCAN_B];
  int i = blockIdx.x * SCAN_B + threadIdx.x;
  int x = (i < n) ? in[i] : 0;
  s[threadIdx.x] = x;
  __syncthreads();
  for (int d = 1; d < SCAN_B; d <<= 1) {
    int v = (threadIdx.x >= d) ? s[threadIdx.x - d] : 0;
    __syncthreads();
    s[threadIdx.x] += v;
    __syncthreads();
  }
  if (i < n) out[i] = s[threadIdx.x] - x;
  if (threadIdx.x == SCAN_B - 1) bsum[blockIdx.x] = s[threadIdx.x];
}

// single-block exclusive scan over nb block sums (carry-chained chunks of 256)
__global__ void scan_mid(const int* __restrict__ bsumA, int* __restrict__ bsumAs, int nb) {
  __shared__ int s[256];
  __shared__ int carry;
  if (threadIdx.x == 0) carry = 0;
  __syncthreads();
  for (int c0 = 0; c0 < nb; c0 += 256) {
    int i = c0 + threadIdx.x;
    int x = (i < nb) ? bsumA[i] : 0;
    s[threadIdx.x] = x;
    __syncthreads();
    for (int d = 1; d < 256; d <<= 1) {
      int v = (threadIdx.x >= d) ? s[threadIdx.x - d] : 0;
      __syncthreads();
      s[threadIdx.x] += v;
      __syncthreads();
    }
    if (i < nb) bsumAs[i] = carry + s[threadIdx.x] - x;
    __syncthreads();
    if (threadIdx.x == 255) carry += s[255];
    __syncthreads();
  }
}

__global__ void scan_apply2(int* __restrict__ rp2, const int* __restrict__ lvl1,
                            int* __restrict__ slot, int n) {
  int i = blockIdx.x * blockDim.x + threadIdx.x;
  if (i >= n) return;
  int v = rp2[i] + lvl1[i >> 8];
  rp2[i] = v;
  slot[i] = v;
}

__global__ void scatter_edges_xcd(const int* __restrict__ ei, const int* __restrict__ et,
                                  int* __restrict__ slot, unsigned* __restrict__ packed) {
  int cls = blockIdx.x & 7;
  unsigned lo = cls * NCHUNK, hi = lo + NCHUNK;
  int e = (blockIdx.x >> 3) * blockDim.x + threadIdx.x;
  int stride = (gridDim.x >> 3) * blockDim.x;
  for (; e < NEDGE; e += stride) {
    unsigned d = (unsigned)ei[NEDGE + e]; if (d >= NNODES) d = 0;
    if (d < lo || d >= hi) continue;
    unsigned s = (unsigned)ei[e];  if (s >= NNODES) s = 0;
    unsigned t = (unsigned)et[e];  if (t >= NREL)  t = 0;
    int pos = atomicAdd(slot + d * NREL + t, 1);
    packed[pos] = s;
  }
}

// ===== layer-1 gather-means: 4 dsts/wave (16-lane quarters), 8-rel rounds ==========
__global__ __launch_bounds__(256) void gather_rounds(
    const int* __restrict__ rp2, const unsigned* __restrict__ packed,
    const int4* __restrict__ xu, unsigned* __restrict__ M9, int d0, int d1) {
  const int lane = threadIdx.x & 63;
  const int qtr = lane >> 4;
  const int sub = lane & 15;
  int wid = (blockIdx.x * blockDim.x + threadIdx.x) >> 6;
  int nw = (gridDim.x * blockDim.x) >> 6;
  for (int p0 = d0 + wid * 4; p0 < d1; p0 += nw * 4) {
    int d = p0 + qtr;
    bool valid = (d < d1);
    int bi = (valid ? d : d0) * NREL;
    int b[9];
#pragma unroll
    for (int q = 0; q < 9; ++q)
      b[q] = (bi + q == NSEG) ? NEDGE : rp2[bi + q];
    int len[8];
    int mx = 0;
#pragma unroll
    for (int q = 0; q < 8; ++q) {
      len[q] = valid ? (b[q + 1] - b[q]) : 0;
      mx = len[q] > mx ? len[q] : mx;
    }
    float a[8][8];
#pragma unroll
    for (int q = 0; q < 8; ++q)
#pragma unroll
      for (int j = 0; j < 8; ++j) a[q][j] = 0.f;
    for (int r = 0; r < mx; ++r) {
#pragma unroll
      for (int q = 0; q < 8; ++q) {
        if (r < len[q]) {
          int4 v = xu[(size_t)packed[b[q] + r] * 16 + sub];
          unsigned u0 = (unsigned)v.x, u1 = (unsigned)v.y;
          unsigned u2 = (unsigned)v.z, u3 = (unsigned)v.w;
          a[q][0] += bf16_bits_to_f32((unsigned short)(u0 & 0xffffu));
          a[q][1] += bf16_bits_to_f32((unsigned short)(u0 >> 16));
          a[q][2] += bf16_bits_to_f32((unsigned short)(u1 & 0xffffu));
          a[q][3] += bf16_bits_to_f32((unsigned short)(u1 >> 16));
          a[q][4] += bf16_bits_to_f32((unsigned short)(u2 & 0xffffu));
          a[q][5] += bf16_bits_to_f32((unsigned short)(u2 >> 16));
          a[q][6] += bf16_bits_to_f32((unsigned short)(u3 & 0xffffu));
          a[q][7] += bf16_bits_to_f32((unsigned short)(u3 >> 16));
        }
      }
    }
    if (valid) {
      unsigned* rowp = M9 + (size_t)(d - d0) * 512;
#pragma unroll
      for (int q = 0; q < 8; ++q) {
        float w = 1.0f / (float)(len[q] > 0 ? len[q] : 1);
        uint4 o;
        o.x = pack_bf16x2(a[q][0] * w, a[q][1] * w);
        o.y = pack_bf16x2(a[q][2] * w, a[q][3] * w);
        o.z = pack_bf16x2(a[q][4] * w, a[q][5] * w);
        o.w = pack_bf16x2(a[q][6] * w, a[q][7] * w);
        *(uint4*)(rowp + q * 64 + sub * 4) = o;
      }
    }
  }
}

// ===== layer-2 aggregation + log_softmax (4 lanes/dst; lane owns 2 relations) ======
__global__ void fused_out(const int* __restrict__ rp2, const unsigned* __restrict__ packed,
                          const float* __restrict__ h2, const float* __restrict__ b2,
                          float* __restrict__ out) {
  int gt = blockIdx.x * blockDim.x + threadIdx.x;
  int d = gt >> 2;
  int l4 = gt & 3;
  if (d >= NNODES) return;
  float z0 = 0.f, z1 = 0.f;
#pragma unroll
  for (int k = 0; k < 2; ++k) {
    int t = l4 * 2 + k;
    int i = d * NREL + t;
    int beg = rp2[i];
    int end = (i == NSEG - 1) ? NEDGE : rp2[i + 1];
    float s0 = 0.f, s1 = 0.f;
    for (int e = beg; e < end; ++e) {
      unsigned s = packed[e];
      s0 += h2[(size_t)s * 18 + t * 2];
      s1 += h2[(size_t)s * 18 + t * 2 + 1];
    }
    int c = end - beg;
    float w = 1.0f / (float)(c > 0 ? c : 1);
    z0 += s0 * w;
    z1 += s1 * w;
  }
  z0 += __shfl_xor(z0, 1, 4); z0 += __shfl_xor(z0, 2, 4);
  z1 += __shfl_xor(z1, 1, 4); z1 += __shfl_xor(z1, 2, 4);
  if (l4 == 0) {
    z0 += h2[(size_t)d * 18 + 16] + b2[0];
    z1 += h2[(size_t)d * 18 + 17] + b2[1];
    float m = fmaxf(z0, z1);
    float l = m + logf(expf(z0 - m) + expf(z1 - m));
    out[(size_t)d * 2 + 0] = z0 - l;
    out[(size_t)d * 2 + 1] = z1 - l;
  }
}

__global__ void fill_sentinel(float* __restrict__ out, int n, float v) {
  int i = blockIdx.x * blockDim.x + threadIdx.x;
  if (i < n) out[i] = v;
}

// ===================================================================================
extern "C" void kernel_launch(void* const* d_in, const int* in_sizes, int n_in,
                              void* d_out, int out_size, void* d_ws, size_t ws_size,
                              hipStream_t stream) {
  const float* x_user = (const float*)d_in[0];
  const float* x_food = (const float*)d_in[1];
  const float* x_ing  = (const float*)d_in[2];
  const float* x_cat  = (const float*)d_in[3];
  const float* x_hab  = (const float*)d_in[4];
  const float* Wu = (const float*)d_in[5];  const float* bu  = (const float*)d_in[6];
  const float* Wf = (const float*)d_in[7];  const float* bfo = (const float*)d_in[8];
  const float* Wi = (const float*)d_in[9];  const float* bi  = (const float*)d_in[10];
  const float* Wc = (const float*)d_in[11]; const float* bc  = (const float*)d_in[12];
  const float* Wh = (const float*)d_in[13]; const float* bh  = (const float*)d_in[14];
  const float* W1 = (const float*)d_in[15]; const float* root1 = (const float*)d_in[16];
  const float* b1 = (const float*)d_in[17];
  const float* W2 = (const float*)d_in[18]; const float* root2 = (const float*)d_in[19];
  const float* b2 = (const float*)d_in[20];
  const int* ei = (const int*)d_in[21];
  const int* et = (const int*)d_in[22];
  (void)in_sizes; (void)n_in;

  dim3 blk(256);
  const int NB_A = (NSEG + SCAN_B - 1) / SCAN_B;   // 3594

  // ---- base layout (~56 MB; x1 buffer eliminated) ----
  char* ws = (char*)d_ws;
  size_t off = 0;
  unsigned short* x_all = (unsigned short*)(ws + off); off += alignup((size_t)NNODES * 128 * 2);
  int* cnt_dt = (int*)(ws + off);        off += alignup((size_t)NSEG * 4);
  int* rp2 = (int*)(ws + off);           off += alignup((size_t)NSEG * 4);
  int* slot = (int*)(ws + off);          off += alignup((size_t)NSEG * 4);
  unsigned* packed = (unsigned*)(ws + off); off += alignup((size_t)NEDGE * 4);
  int* bsumA = (int*)(ws + off);         off += alignup((size_t)4096 * 4);
  int* bsumAs = (int*)(ws + off);        off += alignup((size_t)4096 * 4);
  unsigned short* Wp = (unsigned short*)(ws + off);   off += alignup((size_t)131072 * 2);
  unsigned short* W1rT = (unsigned short*)(ws + off); off += alignup((size_t)128 * 1152 * 2);
  unsigned short* B2pad = (unsigned short*)(ws + off); off += alignup((size_t)128 * 128 * 2);
  float* h2 = (float*)(ws + off);        off += alignup((size_t)NNODES * 18 * 4);
  size_t base = off;

  // pick smallest chunk count whose M9 buffer (1024 cols) fits
  int NCH = 0;
  for (int cand = 1; cand <= 16; cand <<= 1) {
    size_t ch = ((size_t)NNODES + cand - 1) / cand;
    if (base + alignup(ch * 1024 * 2) <= ws_size) { NCH = cand; break; }
  }
  if (NCH == 0) {
    fill_sentinel<<<(out_size + 255) / 256, blk, 0, stream>>>((float*)d_out, out_size, -777.0f);
    return;
  }
  unsigned short* M9 = (unsigned short*)(ws + base);
  const int CH = (NNODES + NCH - 1) / NCH;

  // ---- weight repacks + cnt_dt zero (1 dispatch) ----
  build_all<<<2048, blk, 0, stream>>>(Wu, Wf, Wi, Wc, Wh, W1, root1, W2, root2,
                                      Wp, W1rT, B2pad, cnt_dt);

  // ---- projections -> x_all (1 dispatch, 902 tiles) ----
  {
    ProjP P;
    P.A0 = x_user; P.A1 = x_food; P.A2 = x_ing; P.A3 = x_cat; P.A4 = x_hab;
    P.b0 = bu; P.b1 = bfo; P.b2 = bi; P.b3 = bc; P.b4 = bh;
    P.t1 = 391; P.t2 = 391 + 235; P.t3 = 391 + 235 + 157; P.t4 = 391 + 235 + 157 + 40;
    int ntiles = P.t4 + 79;   // 902
    proj_all<<<dim3(1, ntiles), blk, 0, stream>>>(P, Wp, x_all);
  }

  // ---- (dst,rel)-keyed CSR build (XCD-partitioned) ----
  count_dt_xcd<<<2048, blk, 0, stream>>>(ei, et, cnt_dt);
  scan_block<<<NB_A, SCAN_B, 0, stream>>>(cnt_dt, rp2, bsumA, NSEG);
  scan_mid<<<1, 256, 0, stream>>>(bsumA, bsumAs, NB_A);
  scan_apply2<<<NB_A, SCAN_B, 0, stream>>>(rp2, bsumAs, slot, NSEG);
  scatter_edges_xcd<<<2048, blk, 0, stream>>>(ei, et, slot, packed);

  // ---- layer 1 (+fused layer 2): per dst-chunk gather + K=1152 GEMM -> h2 ----
  for (int c = 0; c < NCH; ++c) {
    int d0 = c * CH;
    int d1 = (d0 + CH < NNODES) ? d0 + CH : NNODES;
    int Mc = d1 - d0;
    int groups = (Mc + 3) / 4;
    int gblocks = (groups + 3) / 4;
    gather_rounds<<<gblocks, blk, 0, stream>>>(rp2, packed, (const int4*)x_all,
                                               (unsigned*)M9, d0, d1);
    dim3 g(1, (Mc + 127) / 128);
    l1_gemm<<<g, blk, 0, stream>>>(M9, x_all, W1rT, b1, B2pad, h2, d0, Mc);
  }

  fused_out<<<(NNODES * 4 + 255) / 256, blk, 0, stream>>>(rp2, packed, h2, b2, (float*)d_out);
}